// Round 1
// baseline (15436.177 us; speedup 1.0000x reference)
//
#include <hip/hip_runtime.h>
#include <hip/hip_bf16.h>

// Problem constants
#define BB 16
#define CIN 7
#define CH 32
#define HH 256
#define WW 256
#define PLANE (HH*WW)           // 65536
#define YELEMS ((size_t)BB*CH*PLANE)  // 33,554,432 floats = 128 MiB

__device__ __forceinline__ float fast_tanh(float x) {
    float xc = fminf(fmaxf(x, -15.f), 15.f);
    float e  = __expf(2.f * xc);
    return (e - 1.f) / (e + 1.f);
}

// ---------------------------------------------------------------------------
// Pad scan weights (CH,CH,5) -> wPad[set][o][i][8] (k=5..7 zero) in d_ws.
// 4 sets x 32 x 32 x 8 = 32768 floats.
__global__ __launch_bounds__(256) void prep_weights(
    float* __restrict__ wPad,
    const float* __restrict__ wu, const float* __restrict__ wd,
    const float* __restrict__ wl, const float* __restrict__ wr)
{
    int idx = blockIdx.x * 256 + threadIdx.x;   // [0, 32768)
    if (idx >= 4 * CH * CH * 8) return;
    int set = idx >> 13;
    int rem = idx & 8191;
    int o = rem >> 8;
    int i = (rem >> 3) & 31;
    int k = rem & 7;
    const float* src = (set == 0) ? wu : (set == 1) ? wd : (set == 2) ? wl : wr;
    wPad[idx] = (k < 5) ? src[(o * CH + i) * 5 + k] : 0.f;
}

// ---------------------------------------------------------------------------
// Init conv: Y[b,o,h,x] = tanh( b_init[o] + sum_{ci,ky,kx} X[b,ci,h+ky-1,x+kx-1]*W[o,ci,ky,kx] )
// grid: (BB*HH) blocks, 256 threads (x). Each thread computes all 32 out-channels.
__global__ __launch_bounds__(256) void init_conv(
    float* __restrict__ Y, const float* __restrict__ X,
    const float* __restrict__ W, const float* __restrict__ bias)
{
    int bh = blockIdx.x;
    int b  = bh >> 8;
    int h  = bh & 255;
    int x  = threadIdx.x;

    float acc[CH];
    #pragma unroll
    for (int o = 0; o < CH; ++o) acc[o] = bias[o];

    for (int ci = 0; ci < CIN; ++ci) {
        #pragma unroll
        for (int ky = 0; ky < 3; ++ky) {
            int y = h + ky - 1;
            if ((unsigned)y >= (unsigned)HH) continue;
            #pragma unroll
            for (int kx = 0; kx < 3; ++kx) {
                int xx = x + kx - 1;
                float v = ((unsigned)xx < (unsigned)WW)
                          ? X[(((size_t)b * CIN + ci) * HH + y) * WW + xx] : 0.f;
                #pragma unroll
                for (int o = 0; o < CH; ++o)
                    acc[o] = fmaf(v, W[((o * CIN + ci) * 3 + ky) * 3 + kx], acc[o]);
            }
        }
    }
    size_t base = ((size_t)b * CH) * PLANE + (size_t)h * WW + x;
    #pragma unroll
    for (int o = 0; o < CH; ++o)
        Y[base + (size_t)o * PLANE] = fast_tanh(acc[o]);
}

// ---------------------------------------------------------------------------
// Directional scan (in-place on Y).
// Element (b,o): plane offset = r*RS + s*SS, where s is the scan index and
// r the within-row index. H-scan: RS=1, SS=256 (s=h, r=x). W-scan: RS=256, SS=1.
// Recurrence: row[s] = row_X[s] + tanh(conv1d_k5(row[s-1])), row[0] unchanged.
// One block per batch; state row (32 x 256) lives in LDS across all steps.
template<int RS, int SS, bool REV>
__global__ __launch_bounds__(1024) void scan_kernel(
    float* __restrict__ Y, const float* __restrict__ wp, const float* __restrict__ bias)
{
    constexpr int PITCH = 264;          // floats per LDS row; 264*4 B = 16B-multiple
    __shared__ float cur[CH * PITCH];   // padded: p = r + 2, pads zeroed

    const int b    = blockIdx.x;
    const int tid  = threadIdx.x;
    const int lane = tid & 63;
    const int o0   = __builtin_amdgcn_readfirstlane(tid >> 6) * 2;  // wave-uniform
    const int r0   = lane << 2;         // 4 positions per lane

    for (int idx = tid; idx < CH * PITCH; idx += 1024) cur[idx] = 0.f;

    float* Y0 = Y + ((size_t)(b * CH + o0)) * PLANE;
    float* Y1 = Y0 + PLANE;
    const float bias0 = bias[o0];
    const float bias1 = bias[o0 + 1];
    const float* wr0 = wp + o0 * 256;   // [i][8] layout per output channel
    const float* wr1 = wr0 + 256;

    __syncthreads();
    {   // load initial row (unchanged output row)
        const int sp = REV ? (HH - 1) : 0;
        #pragma unroll
        for (int j = 0; j < 4; ++j) {
            cur[o0 * PITCH + 2 + r0 + j]       = Y0[(size_t)(r0 + j) * RS + (size_t)sp * SS];
            cur[(o0 + 1) * PITCH + 2 + r0 + j] = Y1[(size_t)(r0 + j) * RS + (size_t)sp * SS];
        }
    }
    __syncthreads();

    for (int s = 1; s < 256; ++s) {
        const int sp = REV ? (255 - s) : s;

        float acc0[4] = {bias0, bias0, bias0, bias0};
        float acc1[4] = {bias1, bias1, bias1, bias1};

        #pragma unroll 4
        for (int i = 0; i < CH; ++i) {
            // inputs x = r0-2 .. r0+5  <=>  p = r0 .. r0+7 : two aligned b128s
            const float4 A  = *(const float4*)&cur[i * PITCH + r0];
            const float4 Bv = *(const float4*)&cur[i * PITCH + r0 + 4];
            const float inv[8] = {A.x, A.y, A.z, A.w, Bv.x, Bv.y, Bv.z, Bv.w};
            const float4 wa  = *(const float4*)(wr0 + i * 8);
            const float  wa4 = wr0[i * 8 + 4];
            const float4 wb  = *(const float4*)(wr1 + i * 8);
            const float  wb4 = wr1[i * 8 + 4];
            const float wk0[5] = {wa.x, wa.y, wa.z, wa.w, wa4};
            const float wk1[5] = {wb.x, wb.y, wb.z, wb.w, wb4};
            #pragma unroll
            for (int k = 0; k < 5; ++k) {
                #pragma unroll
                for (int j = 0; j < 4; ++j) {
                    acc0[j] = fmaf(inv[j + k], wk0[k], acc0[j]);
                    acc1[j] = fmaf(inv[j + k], wk1[k], acc1[j]);
                }
            }
        }

        float v0[4], v1[4];
        if constexpr (RS == 1) {
            const float4 t0 = *(const float4*)(Y0 + (size_t)sp * SS + r0);
            const float4 t1 = *(const float4*)(Y1 + (size_t)sp * SS + r0);
            v0[0] = t0.x; v0[1] = t0.y; v0[2] = t0.z; v0[3] = t0.w;
            v1[0] = t1.x; v1[1] = t1.y; v1[2] = t1.z; v1[3] = t1.w;
        } else {
            #pragma unroll
            for (int j = 0; j < 4; ++j) {
                v0[j] = Y0[(size_t)(r0 + j) * RS + sp];
                v1[j] = Y1[(size_t)(r0 + j) * RS + sp];
            }
        }
        #pragma unroll
        for (int j = 0; j < 4; ++j) {
            v0[j] += fast_tanh(acc0[j]);
            v1[j] += fast_tanh(acc1[j]);
        }

        __syncthreads();   // all conv reads of cur complete

        #pragma unroll
        for (int j = 0; j < 4; ++j) {
            cur[o0 * PITCH + 2 + r0 + j]       = v0[j];
            cur[(o0 + 1) * PITCH + 2 + r0 + j] = v1[j];
        }
        if constexpr (RS == 1) {
            *(float4*)(Y0 + (size_t)sp * SS + r0) = make_float4(v0[0], v0[1], v0[2], v0[3]);
            *(float4*)(Y1 + (size_t)sp * SS + r0) = make_float4(v1[0], v1[1], v1[2], v1[3]);
        } else {
            #pragma unroll
            for (int j = 0; j < 4; ++j) {
                Y0[(size_t)(r0 + j) * RS + sp] = v0[j];
                Y1[(size_t)(r0 + j) * RS + sp] = v1[j];
            }
        }
        __syncthreads();   // writes visible before next step's reads
    }
}

// ---------------------------------------------------------------------------
// Final conv: out[b,0,h,x] = sigmoid( b_end + sum_{ci,ky,kx} Y[b,ci,h+ky-1,x+kx-1]*W[ci,ky,kx] )
__global__ __launch_bounds__(256) void final_conv(
    float* __restrict__ out, const float* __restrict__ Y,
    const float* __restrict__ W, const float* __restrict__ bias)
{
    int bh = blockIdx.x;
    int b  = bh >> 8;
    int h  = bh & 255;
    int x  = threadIdx.x;

    float acc = bias[0];
    for (int ci = 0; ci < CH; ++ci) {
        #pragma unroll
        for (int ky = 0; ky < 3; ++ky) {
            int y = h + ky - 1;
            if ((unsigned)y >= (unsigned)HH) continue;
            #pragma unroll
            for (int kx = 0; kx < 3; ++kx) {
                int xx = x + kx - 1;
                float v = ((unsigned)xx < (unsigned)WW)
                          ? Y[(((size_t)b * CH + ci) * HH + y) * WW + xx] : 0.f;
                acc = fmaf(v, W[(ci * 3 + ky) * 3 + kx], acc);
            }
        }
    }
    float sg = 1.f / (1.f + __expf(-acc));
    out[((size_t)b * HH + h) * WW + x] = sg;
}

// ---------------------------------------------------------------------------
extern "C" void kernel_launch(void* const* d_in, const int* in_sizes, int n_in,
                              void* d_out, int out_size, void* d_ws, size_t ws_size,
                              hipStream_t stream)
{
    const float* X      = (const float*)d_in[0];
    const float* w_init = (const float*)d_in[1];
    const float* b_init = (const float*)d_in[2];
    const float* w_u    = (const float*)d_in[3];
    const float* b_u    = (const float*)d_in[4];
    const float* w_d    = (const float*)d_in[5];
    const float* b_d    = (const float*)d_in[6];
    const float* w_l    = (const float*)d_in[7];
    const float* b_l    = (const float*)d_in[8];
    const float* w_r    = (const float*)d_in[9];
    const float* b_r    = (const float*)d_in[10];
    const float* w_end  = (const float*)d_in[11];
    const float* b_end  = (const float*)d_in[12];
    float* out = (float*)d_out;

    float* Y    = (float*)d_ws;               // 33,554,432 floats (128 MiB)
    float* wPad = Y + YELEMS;                 // 32,768 floats

    prep_weights<<<dim3(128), dim3(256), 0, stream>>>(wPad, w_u, w_d, w_l, w_r);
    init_conv<<<dim3(BB * HH), dim3(256), 0, stream>>>(Y, X, w_init, b_init);

    // up: axis=H, reverse  (RS=1, SS=256)
    scan_kernel<1, 256, true ><<<dim3(BB), dim3(1024), 0, stream>>>(Y, wPad + 0 * 8192, b_u);
    // down: axis=H, forward
    scan_kernel<1, 256, false><<<dim3(BB), dim3(1024), 0, stream>>>(Y, wPad + 1 * 8192, b_d);
    // left: axis=W, reverse (RS=256, SS=1)
    scan_kernel<256, 1, true ><<<dim3(BB), dim3(1024), 0, stream>>>(Y, wPad + 2 * 8192, b_l);
    // right: axis=W, forward
    scan_kernel<256, 1, false><<<dim3(BB), dim3(1024), 0, stream>>>(Y, wPad + 3 * 8192, b_r);

    final_conv<<<dim3(BB * HH), dim3(256), 0, stream>>>(out, Y, w_end, b_end);
}

// Round 2
// 9149.392 us; speedup vs baseline: 1.6871x; 1.6871x over previous
//
#include <hip/hip_runtime.h>
#include <hip/hip_bf16.h>

// Problem constants
#define BB 16
#define CIN 7
#define CH 32
#define HH 256
#define WW 256
#define PLANE (HH*WW)                   // 65536
#define YELEMS ((size_t)BB*CH*PLANE)    // 33,554,432 floats = 128 MiB

typedef _Float16 half2v __attribute__((ext_vector_type(2)));

__device__ __forceinline__ float fast_tanh(float x) {
    float xc = fminf(fmaxf(x, -15.f), 15.f);
    float e  = __expf(2.f * xc);
    return (e - 1.f) / (e + 1.f);
}

__device__ __forceinline__ unsigned packh2(float a, float b) {
    half2v h;
    h.x = (_Float16)a;
    h.y = (_Float16)b;
    return __builtin_bit_cast(unsigned, h);
}

__device__ __forceinline__ float dot2f(unsigned a, unsigned b, float c) {
#if __has_builtin(__builtin_amdgcn_fdot2)
    return __builtin_amdgcn_fdot2(__builtin_bit_cast(half2v, a),
                                  __builtin_bit_cast(half2v, b), c, false);
#else
    half2v ha = __builtin_bit_cast(half2v, a);
    half2v hb = __builtin_bit_cast(half2v, b);
    float r = fmaf((float)ha.x, (float)hb.x, c);
    return fmaf((float)ha.y, (float)hb.y, r);
#endif
}

// ---------------------------------------------------------------------------
// Pack scan weights (CH,CH,5) fp32 -> f16x2 channel-pair dwords.
// Layout: idx = set*4096 + q*256 + g*64 + oo*8 + k   (q=ch-pair 0..15, g=out
// group 0..3, oo=out-within-group 0..7, k=0..7 with k>=5 zero).
// dword = pack(w[o][2q][k], w[o][2q+1][k]), o = g*8+oo.
__global__ __launch_bounds__(256) void prep_weights(
    unsigned* __restrict__ wPk,
    const float* __restrict__ wu, const float* __restrict__ wd,
    const float* __restrict__ wl, const float* __restrict__ wr)
{
    int idx = blockIdx.x * 256 + threadIdx.x;   // [0, 16384)
    if (idx >= 4 * 4096) return;
    int set = idx >> 12;
    int rem = idx & 4095;
    int q   = rem >> 8;
    int g   = (rem >> 6) & 3;
    int oo  = (rem >> 3) & 7;
    int k   = rem & 7;
    int o   = g * 8 + oo;
    const float* src = (set == 0) ? wu : (set == 1) ? wd : (set == 2) ? wl : wr;
    unsigned val = 0;
    if (k < 5)
        val = packh2(src[(o * CH + 2 * q) * 5 + k], src[(o * CH + 2 * q + 1) * 5 + k]);
    wPk[idx] = val;
}

// ---------------------------------------------------------------------------
// Init conv: Y[b,o,h,x] = tanh( conv3x3(X) + b ), fp32.
__global__ __launch_bounds__(256) void init_conv(
    float* __restrict__ Y, const float* __restrict__ X,
    const float* __restrict__ W, const float* __restrict__ bias)
{
    int bh = blockIdx.x;
    int b  = bh >> 8;
    int h  = bh & 255;
    int x  = threadIdx.x;

    float acc[CH];
    #pragma unroll
    for (int o = 0; o < CH; ++o) acc[o] = bias[o];

    for (int ci = 0; ci < CIN; ++ci) {
        #pragma unroll
        for (int ky = 0; ky < 3; ++ky) {
            int y = h + ky - 1;
            if ((unsigned)y >= (unsigned)HH) continue;
            #pragma unroll
            for (int kx = 0; kx < 3; ++kx) {
                int xx = x + kx - 1;
                float v = ((unsigned)xx < (unsigned)WW)
                          ? X[(((size_t)b * CIN + ci) * HH + y) * WW + xx] : 0.f;
                #pragma unroll
                for (int o = 0; o < CH; ++o)
                    acc[o] = fmaf(v, W[((o * CIN + ci) * 3 + ky) * 3 + kx], acc[o]);
            }
        }
    }
    size_t base = ((size_t)b * CH) * PLANE + (size_t)h * WW + x;
    #pragma unroll
    for (int o = 0; o < CH; ++o)
        Y[base + (size_t)o * PLANE] = fast_tanh(acc[o]);
}

// ---------------------------------------------------------------------------
// Directional scan, in-place on fp32 Y. One block per batch image.
// Mapping: wave wv (16 total): g = wv&3 -> output channels g*8..g*8+7,
//          seg = wv>>2 -> positions seg*64 + lane. One position per lane.
// State row kept in LDS as f16 channel-pair dwords: cur[q][2+pos] holds
// (ch 2q, ch 2q+1) at pos. All LDS accesses are lane-stride-1 b32 ->
// conflict-free (2 lanes/bank). Inner product via v_dot2_f32_f16 (fp32 acc).
// Global Y stays fp32, so the additive X term is full precision.
template<int RS, int SS, bool REV>
__global__ __launch_bounds__(1024) void scan_kernel(
    float* __restrict__ Y, const unsigned* __restrict__ wPk,
    const float* __restrict__ bias)
{
    __shared__ unsigned cur[16][260];   // [ch-pair][2 + 256 + 2]

    const int tid  = threadIdx.x;
    const int wv   = __builtin_amdgcn_readfirstlane(tid >> 6);
    const int lane = tid & 63;
    const int g    = wv & 3;
    const int seg  = wv >> 2;
    const int pos  = seg * 64 + lane;
    const int ob   = g * 8;

    // zero LDS pads
    if (tid < 16) {
        cur[tid][0] = 0; cur[tid][1] = 0;
        cur[tid][258] = 0; cur[tid][259] = 0;
    }

    float bs[8];
    #pragma unroll
    for (int oo = 0; oo < 8; ++oo) bs[oo] = bias[ob + oo];

    float* Yb = Y + (size_t)blockIdx.x * CH * PLANE;
    size_t base[8];
    #pragma unroll
    for (int oo = 0; oo < 8; ++oo)
        base[oo] = (size_t)(ob + oo) * PLANE + (size_t)pos * RS;

    // initial row (s=0 output is unchanged input row)
    {
        const int sp = REV ? (HH - 1) : 0;
        float v[8];
        #pragma unroll
        for (int oo = 0; oo < 8; ++oo) v[oo] = Yb[base[oo] + (size_t)sp * SS];
        __syncthreads();
        #pragma unroll
        for (int j = 0; j < 4; ++j)
            cur[g * 4 + j][2 + pos] = packh2(v[2 * j], v[2 * j + 1]);
        __syncthreads();
    }

    for (int s = 1; s < 256; ++s) {
        const int sp = REV ? (255 - s) : s;

        float acc[8];
        #pragma unroll
        for (int oo = 0; oo < 8; ++oo) acc[oo] = bs[oo];

        #pragma unroll 4
        for (int q = 0; q < 16; ++q) {
            // logical positions pos-2..pos+2  ->  phys idx pos..pos+4
            unsigned in0 = cur[q][pos + 0];
            unsigned in1 = cur[q][pos + 1];
            unsigned in2 = cur[q][pos + 2];
            unsigned in3 = cur[q][pos + 3];
            unsigned in4 = cur[q][pos + 4];
            const unsigned* wq = wPk + (q * 4 + g) * 64;   // wave-uniform -> s_load
            #pragma unroll
            for (int oo = 0; oo < 8; ++oo) {
                float a = acc[oo];
                a = dot2f(in0, wq[oo * 8 + 0], a);
                a = dot2f(in1, wq[oo * 8 + 1], a);
                a = dot2f(in2, wq[oo * 8 + 2], a);
                a = dot2f(in3, wq[oo * 8 + 3], a);
                a = dot2f(in4, wq[oo * 8 + 4], a);
                acc[oo] = a;
            }
        }

        float v[8];
        #pragma unroll
        for (int oo = 0; oo < 8; ++oo)
            v[oo] = Yb[base[oo] + (size_t)sp * SS] + fast_tanh(acc[oo]);

        __syncthreads();   // conv reads of cur complete

        #pragma unroll
        for (int j = 0; j < 4; ++j)
            cur[g * 4 + j][2 + pos] = packh2(v[2 * j], v[2 * j + 1]);
        #pragma unroll
        for (int oo = 0; oo < 8; ++oo)
            Yb[base[oo] + (size_t)sp * SS] = v[oo];

        __syncthreads();   // writes visible before next step's reads
    }
}

// ---------------------------------------------------------------------------
// Final conv: sigmoid( conv3x3_{32->1}(Y) + b )
__global__ __launch_bounds__(256) void final_conv(
    float* __restrict__ out, const float* __restrict__ Y,
    const float* __restrict__ W, const float* __restrict__ bias)
{
    int bh = blockIdx.x;
    int b  = bh >> 8;
    int h  = bh & 255;
    int x  = threadIdx.x;

    float acc = bias[0];
    for (int ci = 0; ci < CH; ++ci) {
        #pragma unroll
        for (int ky = 0; ky < 3; ++ky) {
            int y = h + ky - 1;
            if ((unsigned)y >= (unsigned)HH) continue;
            #pragma unroll
            for (int kx = 0; kx < 3; ++kx) {
                int xx = x + kx - 1;
                float v = ((unsigned)xx < (unsigned)WW)
                          ? Y[(((size_t)b * CH + ci) * HH + y) * WW + xx] : 0.f;
                acc = fmaf(v, W[(ci * 3 + ky) * 3 + kx], acc);
            }
        }
    }
    float sg = 1.f / (1.f + __expf(-acc));
    out[((size_t)b * HH + h) * WW + x] = sg;
}

// ---------------------------------------------------------------------------
extern "C" void kernel_launch(void* const* d_in, const int* in_sizes, int n_in,
                              void* d_out, int out_size, void* d_ws, size_t ws_size,
                              hipStream_t stream)
{
    const float* X      = (const float*)d_in[0];
    const float* w_init = (const float*)d_in[1];
    const float* b_init = (const float*)d_in[2];
    const float* w_u    = (const float*)d_in[3];
    const float* b_u    = (const float*)d_in[4];
    const float* w_d    = (const float*)d_in[5];
    const float* b_d    = (const float*)d_in[6];
    const float* w_l    = (const float*)d_in[7];
    const float* b_l    = (const float*)d_in[8];
    const float* w_r    = (const float*)d_in[9];
    const float* b_r    = (const float*)d_in[10];
    const float* w_end  = (const float*)d_in[11];
    const float* b_end  = (const float*)d_in[12];
    float* out = (float*)d_out;

    float*    Y   = (float*)d_ws;             // 128 MiB fp32 state
    unsigned* wPk = (unsigned*)(Y + YELEMS);  // 16384 dwords packed f16x2 weights

    prep_weights<<<dim3(64), dim3(256), 0, stream>>>(wPk, w_u, w_d, w_l, w_r);
    init_conv<<<dim3(BB * HH), dim3(256), 0, stream>>>(Y, X, w_init, b_init);

    // up: axis=H, reverse  (r = x: RS=1, s = h: SS=256)
    scan_kernel<1, 256, true ><<<dim3(BB), dim3(1024), 0, stream>>>(Y, wPk + 0 * 4096, b_u);
    // down: axis=H, forward
    scan_kernel<1, 256, false><<<dim3(BB), dim3(1024), 0, stream>>>(Y, wPk + 1 * 4096, b_d);
    // left: axis=W, reverse (r = h: RS=256, s = w: SS=1)
    scan_kernel<256, 1, true ><<<dim3(BB), dim3(1024), 0, stream>>>(Y, wPk + 2 * 4096, b_l);
    // right: axis=W, forward
    scan_kernel<256, 1, false><<<dim3(BB), dim3(1024), 0, stream>>>(Y, wPk + 3 * 4096, b_r);

    final_conv<<<dim3(BB * HH), dim3(256), 0, stream>>>(out, Y, w_end, b_end);
}

// Round 3
// 5579.362 us; speedup vs baseline: 2.7667x; 1.6399x over previous
//
#include <hip/hip_runtime.h>
#include <hip/hip_bf16.h>

// Problem constants
#define BB 16
#define CIN 7
#define CH 32
#define HH 256
#define WW 256
#define PLANE (HH*WW)                   // 65536
#define YELEMS ((size_t)BB*CH*PLANE)    // 33,554,432 floats = 128 MiB

typedef _Float16 half2v __attribute__((ext_vector_type(2)));
typedef _Float16 half8  __attribute__((ext_vector_type(8)));
typedef float    float4v __attribute__((ext_vector_type(4)));

__device__ __forceinline__ float fast_tanh(float x) {
    float xc = fminf(fmaxf(x, -15.f), 15.f);
    float e  = __expf(2.f * xc);
    return (e - 1.f) / (e + 1.f);
}

__device__ __forceinline__ unsigned packh2(float a, float b) {
    half2v h;
    h.x = (_Float16)a;
    h.y = (_Float16)b;
    return __builtin_bit_cast(unsigned, h);
}

// ---------------------------------------------------------------------------
// Pack scan weights (CH,CH,5) fp32 -> f16 A-fragment order for
// v_mfma_f32_16x16x32_f16.  A[m=lane&15][k=(lane>>4)*8+j], k_global = kt*32+k,
// mapping k_global = tap*32 + ch_in, m -> ch_out = mt*16 + m.
// Flat dword layout per set: (((mt*5 + kt)*64 + lane)*4 + jd), jd packs j=2jd,2jd+1.
// Per set: 2*5*64*4 = 2560 dwords; 4 sets = 10240 dwords (40 KB).
__global__ __launch_bounds__(256) void prep_weights(
    unsigned* __restrict__ wA,
    const float* __restrict__ wu, const float* __restrict__ wd,
    const float* __restrict__ wl, const float* __restrict__ wr)
{
    int idx = blockIdx.x * 256 + threadIdx.x;   // dword index [0, 10240)
    if (idx >= 4 * 2560) return;
    int set = idx / 2560;
    int rem = idx % 2560;
    int mt  = rem / 1280;
    int r2  = rem % 1280;
    int kt  = r2 / 256;
    int r3  = r2 % 256;
    int lane = r3 >> 2;
    int jd   = r3 & 3;
    int m    = lane & 15;
    int quad = lane >> 4;
    int ch_out = mt * 16 + m;
    int ch_in0 = quad * 8 + jd * 2;
    const float* src = (set == 0) ? wu : (set == 1) ? wd : (set == 2) ? wl : wr;
    float a = src[(ch_out * CH + ch_in0) * 5 + kt];
    float b = src[(ch_out * CH + ch_in0 + 1) * 5 + kt];
    wA[idx] = packh2(a, b);
}

// ---------------------------------------------------------------------------
// Init conv: Y[b,o,h,x] = tanh( conv3x3(X) + b ), fp32.
__global__ __launch_bounds__(256) void init_conv(
    float* __restrict__ Y, const float* __restrict__ X,
    const float* __restrict__ W, const float* __restrict__ bias)
{
    int bh = blockIdx.x;
    int b  = bh >> 8;
    int h  = bh & 255;
    int x  = threadIdx.x;

    float acc[CH];
    #pragma unroll
    for (int o = 0; o < CH; ++o) acc[o] = bias[o];

    for (int ci = 0; ci < CIN; ++ci) {
        #pragma unroll
        for (int ky = 0; ky < 3; ++ky) {
            int y = h + ky - 1;
            if ((unsigned)y >= (unsigned)HH) continue;
            #pragma unroll
            for (int kx = 0; kx < 3; ++kx) {
                int xx = x + kx - 1;
                float v = ((unsigned)xx < (unsigned)WW)
                          ? X[(((size_t)b * CIN + ci) * HH + y) * WW + xx] : 0.f;
                #pragma unroll
                for (int o = 0; o < CH; ++o)
                    acc[o] = fmaf(v, W[((o * CIN + ci) * 3 + ky) * 3 + kx], acc[o]);
            }
        }
    }
    size_t base = ((size_t)b * CH) * PLANE + (size_t)h * WW + x;
    #pragma unroll
    for (int o = 0; o < CH; ++o)
        Y[base + (size_t)o * PLANE] = fast_tanh(acc[o]);
}

// ---------------------------------------------------------------------------
// MFMA directional scan, in-place on fp32 Y. One block per batch image.
// Per step: C[32ch x 256pos] = W[32 x 160] * im2col(state) via
// v_mfma_f32_16x16x32_f16.  Wave = one 16-pos N-tile; 2 M-tiles x 5 taps.
// Weights persist in regs as A-frags.  State: f16 LDS [row=pos+2][ch],
// pitch 40 halves (conflict-free b128 B-frag reads), double-buffered ->
// ONE barrier per step.  X-term and global Y stay fp32.
template<int RS, int SS, bool REV>
__global__ __launch_bounds__(1024) void scan_kernel(
    float* __restrict__ Y, const unsigned* __restrict__ wA,
    const float* __restrict__ bias)
{
    constexpr int P = 40;                     // halves per LDS row
    __shared__ _Float16 S[2][260 * P];        // rows: logical pos p at row p+2

    const int tid  = threadIdx.x;
    const int wv   = __builtin_amdgcn_readfirstlane(tid >> 6);
    const int lane = tid & 63;
    const int n    = lane & 15;
    const int quad = lane >> 4;
    const int pos  = wv * 16 + n;

    // --- load persistent A fragments (weights) ---
    half8 afrag[2][5];
    #pragma unroll
    for (int mt = 0; mt < 2; ++mt)
        #pragma unroll
        for (int kt = 0; kt < 5; ++kt) {
            uint4 u = *(const uint4*)(wA + (((mt * 5 + kt) * 64 + lane) << 2));
            afrag[mt][kt] = __builtin_bit_cast(half8, u);
        }

    // --- per-lane bias and global offsets: ch = mt*16 + quad*4 + reg ---
    float bs[2][4];
    size_t gb[2][4];
    float* Yb = Y + (size_t)blockIdx.x * CH * PLANE;
    #pragma unroll
    for (int mt = 0; mt < 2; ++mt)
        #pragma unroll
        for (int r = 0; r < 4; ++r) {
            int ch = mt * 16 + quad * 4 + r;
            bs[mt][r] = bias[ch];
            gb[mt][r] = (size_t)ch * PLANE + (size_t)pos * RS;
        }

    // --- zero pad rows {0,1,258,259} of both buffers ---
    if (tid < 320) {
        int bf  = tid / 160;
        int t   = tid % 160;
        int rr  = t / P;
        int col = t % P;
        int row = (rr < 2) ? rr : (256 + rr);
        S[bf][row * P + col] = (_Float16)0.f;
    }

    // --- initial fill of buf0 with row sp0 (unchanged output row) ---
    {
        const int sp0 = REV ? (HH - 1) : 0;
        int pos0 = tid & 255;
        int cg   = tid >> 8;                  // 0..3 -> channels cg*8..cg*8+7
        float v[8];
        #pragma unroll
        for (int c = 0; c < 8; ++c)
            v[c] = Yb[(size_t)(cg * 8 + c) * PLANE + (size_t)pos0 * RS + (size_t)sp0 * SS];
        uint4 pk;
        pk.x = packh2(v[0], v[1]);
        pk.y = packh2(v[2], v[3]);
        pk.z = packh2(v[4], v[5]);
        pk.w = packh2(v[6], v[7]);
        *(uint4*)&S[0][(pos0 + 2) * P + cg * 8] = pk;
    }
    __syncthreads();

    for (int s = 1; s < 256; ++s) {
        const int sp = REV ? (255 - s) : s;
        const _Float16* Sr = S[(s - 1) & 1];
        _Float16*       Sw = S[s & 1];

        // X-term loads (no deps -> issue early, latency hidden by MFMA)
        float xv[2][4];
        #pragma unroll
        for (int mt = 0; mt < 2; ++mt)
            #pragma unroll
            for (int r = 0; r < 4; ++r)
                xv[mt][r] = Yb[gb[mt][r] + (size_t)sp * SS];

        float4v acc0 = {0.f, 0.f, 0.f, 0.f};
        float4v acc1 = {0.f, 0.f, 0.f, 0.f};
        #pragma unroll
        for (int kt = 0; kt < 5; ++kt) {
            // B[k=quad*8+j][n] = state[ch=quad*8+j][pos + kt - 2] (row pos+kt)
            half8 bf = *(const half8*)(Sr + (pos + kt) * P + quad * 8);
            acc0 = __builtin_amdgcn_mfma_f32_16x16x32_f16(afrag[0][kt], bf, acc0, 0, 0, 0);
            acc1 = __builtin_amdgcn_mfma_f32_16x16x32_f16(afrag[1][kt], bf, acc1, 0, 0, 0);
        }

        // epilogue: v = X + tanh(conv + bias); store global + LDS(next buf)
        float v0[4], v1[4];
        #pragma unroll
        for (int r = 0; r < 4; ++r) {
            v0[r] = xv[0][r] + fast_tanh(acc0[r] + bs[0][r]);
            v1[r] = xv[1][r] + fast_tanh(acc1[r] + bs[1][r]);
        }
        #pragma unroll
        for (int r = 0; r < 4; ++r) {
            Yb[gb[0][r] + (size_t)sp * SS] = v0[r];
            Yb[gb[1][r] + (size_t)sp * SS] = v1[r];
        }
        uint2 pk0, pk1;
        pk0.x = packh2(v0[0], v0[1]); pk0.y = packh2(v0[2], v0[3]);
        pk1.x = packh2(v1[0], v1[1]); pk1.y = packh2(v1[2], v1[3]);
        *(uint2*)&Sw[(pos + 2) * P + 0  + quad * 4] = pk0;   // ch = quad*4+r
        *(uint2*)&Sw[(pos + 2) * P + 16 + quad * 4] = pk1;   // ch = 16+quad*4+r

        __syncthreads();   // writes to Sw visible; prev reads of Sw's buffer done
    }
}

// ---------------------------------------------------------------------------
// Final conv: sigmoid( conv3x3_{32->1}(Y) + b )
__global__ __launch_bounds__(256) void final_conv(
    float* __restrict__ out, const float* __restrict__ Y,
    const float* __restrict__ W, const float* __restrict__ bias)
{
    int bh = blockIdx.x;
    int b  = bh >> 8;
    int h  = bh & 255;
    int x  = threadIdx.x;

    float acc = bias[0];
    for (int ci = 0; ci < CH; ++ci) {
        #pragma unroll
        for (int ky = 0; ky < 3; ++ky) {
            int y = h + ky - 1;
            if ((unsigned)y >= (unsigned)HH) continue;
            #pragma unroll
            for (int kx = 0; kx < 3; ++kx) {
                int xx = x + kx - 1;
                float v = ((unsigned)xx < (unsigned)WW)
                          ? Y[(((size_t)b * CH + ci) * HH + y) * WW + xx] : 0.f;
                acc = fmaf(v, W[(ci * 3 + ky) * 3 + kx], acc);
            }
        }
    }
    float sg = 1.f / (1.f + __expf(-acc));
    out[((size_t)b * HH + h) * WW + x] = sg;
}

// ---------------------------------------------------------------------------
extern "C" void kernel_launch(void* const* d_in, const int* in_sizes, int n_in,
                              void* d_out, int out_size, void* d_ws, size_t ws_size,
                              hipStream_t stream)
{
    const float* X      = (const float*)d_in[0];
    const float* w_init = (const float*)d_in[1];
    const float* b_init = (const float*)d_in[2];
    const float* w_u    = (const float*)d_in[3];
    const float* b_u    = (const float*)d_in[4];
    const float* w_d    = (const float*)d_in[5];
    const float* b_d    = (const float*)d_in[6];
    const float* w_l    = (const float*)d_in[7];
    const float* b_l    = (const float*)d_in[8];
    const float* w_r    = (const float*)d_in[9];
    const float* b_r    = (const float*)d_in[10];
    const float* w_end  = (const float*)d_in[11];
    const float* b_end  = (const float*)d_in[12];
    float* out = (float*)d_out;

    float*    Y  = (float*)d_ws;              // 128 MiB fp32 state
    unsigned* wA = (unsigned*)(Y + YELEMS);   // 10240 dwords f16 A-fragments

    prep_weights<<<dim3(40), dim3(256), 0, stream>>>(wA, w_u, w_d, w_l, w_r);
    init_conv<<<dim3(BB * HH), dim3(256), 0, stream>>>(Y, X, w_init, b_init);

    // up: axis=H, reverse  (r = x: RS=1, s = h: SS=256)
    scan_kernel<1, 256, true ><<<dim3(BB), dim3(1024), 0, stream>>>(Y, wA + 0 * 2560, b_u);
    // down: axis=H, forward
    scan_kernel<1, 256, false><<<dim3(BB), dim3(1024), 0, stream>>>(Y, wA + 1 * 2560, b_d);
    // left: axis=W, reverse (r = h: RS=256, s = w: SS=1)
    scan_kernel<256, 1, true ><<<dim3(BB), dim3(1024), 0, stream>>>(Y, wA + 2 * 2560, b_l);
    // right: axis=W, forward
    scan_kernel<256, 1, false><<<dim3(BB), dim3(1024), 0, stream>>>(Y, wA + 3 * 2560, b_r);

    final_conv<<<dim3(BB * HH), dim3(256), 0, stream>>>(out, Y, w_end, b_end);
}